// Round 3
// baseline (225.348 us; speedup 1.0000x reference)
//
#include <hip/hip_runtime.h>

// out[b,o] = x[b,:] @ W_lin[:,o] + x[b] @ W_nl[o] @ x[b]
// GEMM out = z @ Wz with z[b, 32i+j] = x[b,i]*x[b,j] (K=1024) + linear tail,
// via v_mfma_f32_16x16x32_bf16.
//
// R3 structure: N-split across waves (each wave owns one 16-col n-half, FULL
// K), all 33 B-fragments register-resident (32 bf16x8 = 128 VGPR + linear).
// No LDS, no barriers, no inter-wave reduction. Per 16-row tile a wave loads
// only its lane's x-row, synthesizes A-fragments (fp32 product -> bf16,
// single rounding), runs 33 MFMAs into two interleaved acc chains, stores
// directly. Ping-pong software prefetch of the next tile's x hides global
// load latency under the current tile's VALU+MFMA work.

typedef __attribute__((ext_vector_type(8))) __bf16 bf16x8;
typedef __attribute__((ext_vector_type(4))) float floatx4;

#define NB       524288
#define NTILES   (NB / 16)        // 32768
#define NBLK     512
#define NWAVES   (NBLK * 4)       // 2048 waves
#define TWSTRIDE (NWAVES / 2)     // 1024 tile-wave pairs
#define NJOB     (NTILES / TWSTRIDE)  // 32 tiles per wave (even)

__global__ __launch_bounds__(256, 2)
void nnode_kernel(const float* __restrict__ x, const float* __restrict__ Wlin,
                  const float* __restrict__ Wnl, float* __restrict__ out) {
    const int tid  = threadIdx.x;
    const int wave = tid >> 6;
    const int lane = tid & 63;
    const int q    = lane >> 4;       // quad: A k-window / C row group
    const int col  = lane & 15;       // A row / output column (within n-half)

    const int gw   = blockIdx.x * 4 + wave;
    const int nh   = gw & 1;          // n-half: output cols [16nh, 16nh+16)
    const int tw   = gw >> 1;         // tile-stream id, [0, 1024)
    const int ocol = col + 16 * nh;

    // ---- B fragments (full K) for this wave's n-half, register-resident ----
    // B[k = q*8+j][n = ocol] = W_nl[o = ocol][i = ks][j' = q*8+j]
    bf16x8 bW[32];
    #pragma unroll
    for (int ks = 0; ks < 32; ++ks) {
        const float* src = Wnl + (size_t)ocol * 1024 + ks * 32 + q * 8;
        floatx4 a = *(const floatx4*)(src);
        floatx4 b = *(const floatx4*)(src + 4);
        bf16x8 v;
        #pragma unroll
        for (int j = 0; j < 4; ++j) { v[j] = (__bf16)a[j]; v[j + 4] = (__bf16)b[j]; }
        bW[ks] = v;
    }
    // linear-part B fragment: B[k = q*8+j][n = ocol] = W_lin[k][ocol]
    bf16x8 bl;
    #pragma unroll
    for (int j = 0; j < 8; ++j) bl[j] = (__bf16)Wlin[(q * 8 + j) * 32 + ocol];

    // ---- per-tile load / compute helpers (inlined) ----
    auto loadT = [&](int tile, floatx4* xv, floatx4& w0, floatx4& w1) {
        const float* xr = x + (size_t)((tile << 4) + col) * 32;
        #pragma unroll
        for (int c = 0; c < 8; ++c) xv[c] = *(const floatx4*)(xr + c * 4);
        w0 = *(const floatx4*)(xr + q * 8);
        w1 = *(const floatx4*)(xr + q * 8 + 4);
    };

    auto computeT = [&](int tile, const floatx4* xv, floatx4 w0, floatx4 w1) {
        floatx4 acc0 = {0.f, 0.f, 0.f, 0.f};
        floatx4 acc1 = {0.f, 0.f, 0.f, 0.f};
        // linear tail: A element = x[b, q*8+j]
        {
            bf16x8 af;
            #pragma unroll
            for (int j = 0; j < 4; ++j) { af[j] = (__bf16)w0[j]; af[j + 4] = (__bf16)w1[j]; }
            acc1 = __builtin_amdgcn_mfma_f32_16x16x32_bf16(af, bl, acc1, 0, 0, 0);
        }
        #pragma unroll
        for (int ks = 0; ks < 32; ++ks) {
            const float s = xv[ks >> 2][ks & 3];   // static after unroll
            bf16x8 af;
            #pragma unroll
            for (int j = 0; j < 4; ++j) {
                af[j]     = (__bf16)(s * w0[j]);
                af[j + 4] = (__bf16)(s * w1[j]);
            }
            if (ks & 1)
                acc1 = __builtin_amdgcn_mfma_f32_16x16x32_bf16(af, bW[ks], acc1, 0, 0, 0);
            else
                acc0 = __builtin_amdgcn_mfma_f32_16x16x32_bf16(af, bW[ks], acc0, 0, 0, 0);
        }
        // C/D layout: col = lane&15, row = q*4 + r
        float* orow = out + (size_t)((tile << 4) + q * 4) * 32 + ocol;
        #pragma unroll
        for (int r = 0; r < 4; ++r) orow[(size_t)r * 32] = acc0[r] + acc1[r];
    };

    // ---- ping-pong prefetch over this wave's 32 tiles ----
    floatx4 xvA[8], xvB[8];
    floatx4 wA0, wA1, wB0, wB1;

    loadT(tw, xvA, wA0, wA1);
    #pragma unroll 1
    for (int j = 0; j < NJOB; j += 2) {
        const int tA = tw + j * TWSTRIDE;
        const int tB = tA + TWSTRIDE;
        loadT(tB, xvB, wB0, wB1);
        computeT(tA, xvA, wA0, wA1);
        const int tN = (j + 2 < NJOB) ? tB + TWSTRIDE : tw;  // harmless reload at end
        loadT(tN, xvA, wA0, wA1);
        computeT(tB, xvB, wB0, wB1);
    }
}

extern "C" void kernel_launch(void* const* d_in, const int* in_sizes, int n_in,
                              void* d_out, int out_size, void* d_ws, size_t ws_size,
                              hipStream_t stream) {
    const float* x    = (const float*)d_in[0];
    const float* Wlin = (const float*)d_in[1];
    const float* Wnl  = (const float*)d_in[2];
    float* out        = (float*)d_out;
    nnode_kernel<<<dim3(NBLK), dim3(256), 0, stream>>>(x, Wlin, Wnl, out);
}